// Round 1
// baseline (30972.241 us; speedup 1.0000x reference)
//
#include <hip/hip_runtime.h>

// ---------------------------------------------------------------------------
// Persistent 2-layer LSTM, MI355X.
// 8 groups (blockIdx%8 -> XCD-affine), 32 WGs/group, 8 batches/group.
// Weights live in VGPRs as MFMA B-fragments for all 1024 steps.
// h0/h1 double-buffered in d_ws (fp16); 2 group barriers per step.
// ---------------------------------------------------------------------------

#define T_STEPS 1024
#define WS_BAR_OFF 0                 // 8 groups * 128 B
#define WS_H0_OFF  1024              // [8 groups][2 parity][8 batch][512] f16
#define WS_H1_OFF  (1024 + 8*2*8*512*2)
#define WS_NEED    (WS_H1_OFF + 8*2*8*512*2)   // 263168 bytes

typedef _Float16 f16;
typedef _Float16 f16x8 __attribute__((ext_vector_type(8)));
typedef float    f32x4 __attribute__((ext_vector_type(4)));

__device__ __forceinline__ float sigm_(float x) {
    x = fminf(fmaxf(x, -30.f), 30.f);
    return 1.f / (1.f + __expf(-x));
}
__device__ __forceinline__ float tanh_(float x) {
    x = fminf(fmaxf(x, -15.f), 15.f);
    float e = __expf(-2.f * x);
    return (1.f - e) / (1.f + e);
}

// A-fragment for 16x16x32 f16 MFMA: A[m=lane&15][k=(lane>>4)*8+j]
// m = batch (0..7 valid, 8..15 -> zeros). h plane layout: [batch][512] f16.
__device__ __forceinline__ f16x8 load_afrag(const f16* __restrict__ h, int kbase,
                                            int b, int q) {
    if (b < 8) {
        return *(const f16x8*)(h + b * 512 + kbase + q * 8);
    }
    f16x8 z = {(_Float16)0, (_Float16)0, (_Float16)0, (_Float16)0,
               (_Float16)0, (_Float16)0, (_Float16)0, (_Float16)0};
    return z;
}

__device__ __forceinline__ f16x8 pack8(float4 a, float4 b) {
    f16x8 f;
    f[0] = (f16)a.x; f[1] = (f16)a.y; f[2] = (f16)a.z; f[3] = (f16)a.w;
    f[4] = (f16)b.x; f[5] = (f16)b.y; f[6] = (f16)b.z; f[7] = (f16)b.w;
    return f;
}

// Monotone-counter group barrier: 32 WGs per group. Release-add publishes the
// WG's prior global writes; acquire poll invalidates stale cache on the way out.
__device__ __forceinline__ void group_barrier(unsigned* cnt, unsigned target) {
    __syncthreads();
    if (threadIdx.x == 0) {
        __hip_atomic_fetch_add(cnt, 1u, __ATOMIC_RELEASE, __HIP_MEMORY_SCOPE_AGENT);
        int spins = 0;
        while (__hip_atomic_load(cnt, __ATOMIC_ACQUIRE, __HIP_MEMORY_SCOPE_AGENT) < target) {
            __builtin_amdgcn_s_sleep(2);
            if (++spins > (1 << 22)) break;   // anti-hang safety valve
        }
    }
    __syncthreads();
}

__global__ void zero_ws_kernel(unsigned* __restrict__ p, int ndw) {
    int i = blockIdx.x * blockDim.x + threadIdx.x;
    int stride = gridDim.x * blockDim.x;
    for (; i < ndw; i += stride) p[i] = 0u;
}

__global__ __launch_bounds__(256, 1)
void lstm_persist(const float* __restrict__ x,
                  const float* __restrict__ Wx0, const float* __restrict__ bx0,
                  const float* __restrict__ Wh0,
                  const float* __restrict__ Wx1, const float* __restrict__ bx1,
                  const float* __restrict__ Wh1,
                  const float* __restrict__ Wo,  const float* __restrict__ bo,
                  float* __restrict__ out, char* __restrict__ ws) {
    struct SM {
        float g[4][16][16];      // per-wave gate pre-activation tiles
        float c[2][8][16];       // cell state [layer][batch][unit]
        float bias[2][4][16];    // bx slices  [layer][gate][unit]
        char  pad[78 * 1024];    // force <=1 WG/CU (2 x ~83KB > 160KB LDS)
    };
    __shared__ SM sm;
    const int tid = threadIdx.x;
    if (tid == 0x00FFFFFFu) sm.pad[0] = 1;   // keep pad alive

    const int bid  = blockIdx.x;
    const int g    = bid & 7;     // group (XCD-affine under round-robin)
    const int cu   = bid >> 3;    // 0..31 within group
    const int w    = tid >> 6;    // wave id = gate type (i,f,g,o)
    const int lane = tid & 63;
    const int ln   = lane & 15;   // B-frag: gate-row-within-tile; A-frag: batch
    const int q    = lane >> 4;   // quad -> k-offset/8

    unsigned* barp = (unsigned*)(ws + WS_BAR_OFF) + g * 32;
    f16* H0g = (f16*)(ws + WS_H0_OFF) + g * 8192;   // 2 planes x (8*512)
    f16* H1g = (f16*)(ws + WS_H1_OFF) + g * 8192;

    // ---- LDS init -------------------------------------------------------
    if (tid < 256) ((float*)sm.c)[tid] = 0.f;       // 2*8*16 = 256 floats
    if (tid < 128) {
        int u = tid & 15, w2 = (tid >> 4) & 3, L = tid >> 6;
        const float* bx = L ? bx1 : bx0;
        sm.bias[L][w2][u] = bx[(w2 << 9) + (cu << 4) + u];
    }

    // ---- load persistent weight fragments into registers ----------------
    // B-frag: B[n=lane&15][k=(lane>>4)*8+j], n = gate row, B = W row (W[n][k]).
    const int row = (w << 9) + (cu << 4) + ln;      // gate row in [0,2048)
    f16x8 B0[17];   // layer0: k = [Wh0(512) ; Wx0(21 pad 32)]  -> K=544
    f16x8 B1[32];   // layer1: k = [Wx1(512) ; Wh1(512)]        -> K=1024
    {
        const float* wh0r = Wh0 + (size_t)row * 512;
#pragma unroll
        for (int kk = 0; kk < 16; ++kk) {
            const float* p = wh0r + kk * 32 + q * 8;
            B0[kk] = pack8(*(const float4*)p, *(const float4*)(p + 4));
        }
        {
            const float* wx0r = Wx0 + (size_t)row * 21;
            f16x8 f;
#pragma unroll
            for (int j = 0; j < 8; ++j) {
                int kl = q * 8 + j;
                f[j] = (f16)((kl < 21) ? wx0r[kl] : 0.f);
            }
            B0[16] = f;
        }
        const float* wx1r = Wx1 + (size_t)row * 512;
        const float* wh1r = Wh1 + (size_t)row * 512;
#pragma unroll
        for (int kk = 0; kk < 32; ++kk) {
            int k0 = kk * 32 + q * 8;
            const float* p = (k0 < 512) ? (wx1r + k0) : (wh1r + (k0 - 512));
            B1[kk] = pack8(*(const float4*)p, *(const float4*)(p + 4));
        }
    }
    __syncthreads();

    unsigned gen = 0;

    for (int t = 0; t < T_STEPS; ++t) {
        const int wr = t & 1, rd = wr ^ 1;
        const f16* h0rd = H0g + rd * 4096;
        f16*       h0wr = H0g + wr * 4096;
        const f16* h1rd = H1g + rd * 4096;
        f16*       h1wr = H1g + wr * 4096;

        // ================= layer 0 =================
        f16x8 xf;
        {
            const float* xp = x + ((size_t)(g * 8 + ln) * 1024 + t) * 21;
#pragma unroll
            for (int j = 0; j < 8; ++j) {
                int kl = q * 8 + j;
                float v = (ln < 8 && kl < 21) ? xp[kl] : 0.f;
                xf[j] = (f16)v;
            }
        }
        f32x4 a0 = {0, 0, 0, 0}, a1 = {0, 0, 0, 0};
#pragma unroll
        for (int kk = 0; kk < 16; kk += 2) {
            f16x8 A0 = load_afrag(h0rd, kk * 32, ln, q);
            f16x8 A1 = load_afrag(h0rd, kk * 32 + 32, ln, q);
            a0 = __builtin_amdgcn_mfma_f32_16x16x32_f16(A0, B0[kk], a0, 0, 0, 0);
            a1 = __builtin_amdgcn_mfma_f32_16x16x32_f16(A1, B0[kk + 1], a1, 0, 0, 0);
        }
        a0 = __builtin_amdgcn_mfma_f32_16x16x32_f16(xf, B0[16], a0, 0, 0, 0);
        f32x4 acc = a0 + a1;
        // D layout: row m=(lane>>4)*4+r (batch), col n=lane&15 (unit)
#pragma unroll
        for (int r = 0; r < 4; ++r) sm.g[w][q * 4 + r][ln] = acc[r];
        __syncthreads();
        if (tid < 128) {
            int b = tid & 7, u = tid >> 3;
            float gi = sm.g[0][b][u] + sm.bias[0][0][u];
            float gf = sm.g[1][b][u] + sm.bias[0][1][u];
            float gg = sm.g[2][b][u] + sm.bias[0][2][u];
            float go = sm.g[3][b][u] + sm.bias[0][3][u];
            float iv = sigm_(gi), fv = sigm_(gf), gv = tanh_(gg), ov = sigm_(go);
            float c = sm.c[0][b][u];
            float cn = fv * c + iv * gv;
            sm.c[0][b][u] = cn;
            h0wr[b * 512 + (cu << 4) + u] = (f16)(ov * tanh_(cn));
        }
        group_barrier(barp, ++gen * 32);   // h0(t) now visible group-wide

        // ================= layer 1 =================
        f32x4 c0v = {0, 0, 0, 0}, c1v = {0, 0, 0, 0};
#pragma unroll
        for (int kk = 0; kk < 16; kk += 2) {
            f16x8 A0 = load_afrag(h0wr, kk * 32, ln, q);
            f16x8 A1 = load_afrag(h0wr, kk * 32 + 32, ln, q);
            c0v = __builtin_amdgcn_mfma_f32_16x16x32_f16(A0, B1[kk], c0v, 0, 0, 0);
            c1v = __builtin_amdgcn_mfma_f32_16x16x32_f16(A1, B1[kk + 1], c1v, 0, 0, 0);
        }
#pragma unroll
        for (int kk = 16; kk < 32; kk += 2) {
            f16x8 A0 = load_afrag(h1rd, kk * 32 - 512, ln, q);
            f16x8 A1 = load_afrag(h1rd, kk * 32 - 480, ln, q);
            c0v = __builtin_amdgcn_mfma_f32_16x16x32_f16(A0, B1[kk], c0v, 0, 0, 0);
            c1v = __builtin_amdgcn_mfma_f32_16x16x32_f16(A1, B1[kk + 1], c1v, 0, 0, 0);
        }
        acc = c0v + c1v;
#pragma unroll
        for (int r = 0; r < 4; ++r) sm.g[w][q * 4 + r][ln] = acc[r];
        __syncthreads();
        if (tid < 128) {
            int b = tid & 7, u = tid >> 3;
            float gi = sm.g[0][b][u] + sm.bias[1][0][u];
            float gf = sm.g[1][b][u] + sm.bias[1][1][u];
            float gg = sm.g[2][b][u] + sm.bias[1][2][u];
            float go = sm.g[3][b][u] + sm.bias[1][3][u];
            float iv = sigm_(gi), fv = sigm_(gf), gv = tanh_(gg), ov = sigm_(go);
            float c = sm.c[1][b][u];
            float cn = fv * c + iv * gv;
            sm.c[1][b][u] = cn;
            h1wr[b * 512 + (cu << 4) + u] = (f16)(ov * tanh_(cn));
        }
        group_barrier(barp, ++gen * 32);   // h1(t) now visible group-wide

        // ========== output projection: 5 (b,o) pairs per CU ==========
        if (tid < 5) {
            int idx = cu * 5 + tid;          // 0..159
            int b = idx / 20, o = idx % 20;
            const f16* hp = h1wr + b * 512;
            const float* wo = Wo + (size_t)o * 512;
            float a = bo[o];
#pragma unroll 4
            for (int k = 0; k < 512; k += 8) {
                f16x8 hv = *(const f16x8*)(hp + k);
                float4 wa = *(const float4*)(wo + k);
                float4 wb = *(const float4*)(wo + k + 4);
                a += (float)hv[0] * wa.x + (float)hv[1] * wa.y +
                     (float)hv[2] * wa.z + (float)hv[3] * wa.w +
                     (float)hv[4] * wb.x + (float)hv[5] * wb.y +
                     (float)hv[6] * wb.z + (float)hv[7] * wb.w;
            }
            out[((size_t)(g * 8 + b) * 1024 + t) * 20 + o] = sigm_(a);
        }
    }
}

extern "C" void kernel_launch(void* const* d_in, const int* in_sizes, int n_in,
                              void* d_out, int out_size, void* d_ws, size_t ws_size,
                              hipStream_t stream) {
    const float* x   = (const float*)d_in[0];
    const float* Wx0 = (const float*)d_in[1];
    const float* bx0 = (const float*)d_in[2];
    const float* Wh0 = (const float*)d_in[3];
    const float* Wx1 = (const float*)d_in[4];
    const float* bx1 = (const float*)d_in[5];
    const float* Wh1 = (const float*)d_in[6];
    const float* Wo  = (const float*)d_in[7];
    const float* bo  = (const float*)d_in[8];
    float* out = (float*)d_out;
    char*  ws  = (char*)d_ws;

    if (ws_size < (size_t)WS_NEED) return;   // fail visibly (out stays poisoned)

    zero_ws_kernel<<<64, 256, 0, stream>>>((unsigned*)ws, WS_NEED / 4);
    lstm_persist<<<256, 256, 0, stream>>>(x, Wx0, bx0, Wh0, Wx1, bx1, Wh1,
                                          Wo, bo, out, ws);
}

// Round 2
// 26992.856 us; speedup vs baseline: 1.1474x; 1.1474x over previous
//
#include <hip/hip_runtime.h>

// ---------------------------------------------------------------------------
// Persistent 2-layer LSTM, MI355X.
// 8 groups (blockIdx%8 -> XCD-affine heuristic), 32 WGs/group, 8 batches/group.
// Weights live in VGPRs as MFMA B-fragments for all 1024 steps.
// h0/h1 double-buffered in d_ws (fp16).
// Barrier protocol (round 2 fix): RELAXED atomic polling (no cache maintenance
// per poll), ONE agent-acquire fence (buffer_inv) per crossing, release-add
// publish. Layer-1 GEMM split so barrier waits are covered by compute.
// ---------------------------------------------------------------------------

#define T_STEPS 1024
#define WS_BAR_OFF 0                      // 8 groups * 2 counters * 128 B
#define WS_H0_OFF  2048                   // [8 g][2 parity][8 batch][512] f16
#define WS_H1_OFF  (2048 + 8*2*8*512*2)
#define WS_NEED    (WS_H1_OFF + 8*2*8*512*2)   // 264192 bytes

typedef _Float16 f16;
typedef _Float16 f16x8 __attribute__((ext_vector_type(8)));
typedef float    f32x4 __attribute__((ext_vector_type(4)));

__device__ __forceinline__ float sigm_(float x) {
    x = fminf(fmaxf(x, -30.f), 30.f);
    return 1.f / (1.f + __expf(-x));
}
__device__ __forceinline__ float tanh_(float x) {
    x = fminf(fmaxf(x, -15.f), 15.f);
    float e = __expf(-2.f * x);
    return (1.f - e) / (1.f + e);
}

// A-fragment for 16x16x32 f16 MFMA: A[m=lane&15][k=(lane>>4)*8+j]
// m = batch (0..7 valid, 8..15 -> zeros). h plane layout: [batch][512] f16.
__device__ __forceinline__ f16x8 load_afrag(const f16* __restrict__ h, int kbase,
                                            int b, int q) {
    if (b < 8) {
        return *(const f16x8*)(h + b * 512 + kbase + q * 8);
    }
    f16x8 z = {(_Float16)0, (_Float16)0, (_Float16)0, (_Float16)0,
               (_Float16)0, (_Float16)0, (_Float16)0, (_Float16)0};
    return z;
}

__device__ __forceinline__ f16x8 pack8(float4 a, float4 b) {
    f16x8 f;
    f[0] = (f16)a.x; f[1] = (f16)a.y; f[2] = (f16)a.z; f[3] = (f16)a.w;
    f[4] = (f16)b.x; f[5] = (f16)b.y; f[6] = (f16)b.z; f[7] = (f16)b.w;
    return f;
}

// RELAXED poll — no cache maintenance per iteration (the round-1 bug was an
// ACQUIRE poll: buffer_inv per spin -> L2 thrash, 340 MB HBM traffic).
__device__ __forceinline__ void spin_until(unsigned* cnt, unsigned target) {
    int spins = 0;
    while (__hip_atomic_load(cnt, __ATOMIC_RELAXED, __HIP_MEMORY_SCOPE_AGENT) < target) {
        __builtin_amdgcn_s_sleep(1);
        if (++spins > (1 << 22)) break;   // anti-hang safety valve
    }
}

__global__ void zero_ws_kernel(unsigned* __restrict__ p, int ndw) {
    int i = blockIdx.x * blockDim.x + threadIdx.x;
    int stride = gridDim.x * blockDim.x;
    for (; i < ndw; i += stride) p[i] = 0u;
}

__global__ __launch_bounds__(256, 1)
void lstm_persist(const float* __restrict__ x,
                  const float* __restrict__ Wx0, const float* __restrict__ bx0,
                  const float* __restrict__ Wh0,
                  const float* __restrict__ Wx1, const float* __restrict__ bx1,
                  const float* __restrict__ Wh1,
                  const float* __restrict__ Wo,  const float* __restrict__ bo,
                  float* __restrict__ out, char* __restrict__ ws) {
    struct SM {
        float g[4][16][16];      // per-wave gate pre-activation tiles
        float c[2][8][16];       // cell state [layer][batch][unit]
        float bias[2][4][16];    // bx slices  [layer][gate][unit]
        char  pad[78 * 1024];    // force <=1 WG/CU (2 x ~83KB > 160KB LDS)
    };
    __shared__ SM sm;
    const int tid = threadIdx.x;
    if (tid == 0x00FFFFFFu) sm.pad[0] = 1;   // keep pad alive

    const int bid  = blockIdx.x;
    const int g    = bid & 7;     // group (XCD-affine under round-robin)
    const int cu   = bid >> 3;    // 0..31 within group
    const int w    = tid >> 6;    // wave id = gate type (i,f,g,o)
    const int lane = tid & 63;
    const int ln   = lane & 15;   // B-frag: gate-row-within-tile; A-frag: batch
    const int q    = lane >> 4;   // quad -> k-offset/8

    unsigned* cntA = (unsigned*)(ws + WS_BAR_OFF) + g * 64;        // h0 barrier
    unsigned* cntB = (unsigned*)(ws + WS_BAR_OFF) + g * 64 + 32;   // h1 barrier
    f16* H0g = (f16*)(ws + WS_H0_OFF) + g * 8192;   // 2 planes x (8*512)
    f16* H1g = (f16*)(ws + WS_H1_OFF) + g * 8192;

    // ---- LDS init -------------------------------------------------------
    ((float*)sm.c)[tid & 255] = 0.f;               // 2*8*16 = 256 floats
    if (tid < 128) {
        int u = tid & 15, w2 = (tid >> 4) & 3, L = tid >> 6;
        const float* bx = L ? bx1 : bx0;
        sm.bias[L][w2][u] = bx[(w2 << 9) + (cu << 4) + u];
    }

    // ---- load persistent weight fragments into registers ----------------
    // B-frag: B[n=lane&15][k=(lane>>4)*8+j], n = gate row, B = W row (W[n][k]).
    const int row = (w << 9) + (cu << 4) + ln;      // gate row in [0,2048)
    f16x8 B0[17];   // layer0: k = [Wh0(512) ; Wx0(21 pad 32)]  -> K=544
    f16x8 B1[32];   // layer1: k = [Wx1(512) ; Wh1(512)]        -> K=1024
    {
        const float* wh0r = Wh0 + (size_t)row * 512;
#pragma unroll
        for (int kk = 0; kk < 16; ++kk) {
            const float* p = wh0r + kk * 32 + q * 8;
            B0[kk] = pack8(*(const float4*)p, *(const float4*)(p + 4));
        }
        {
            const float* wx0r = Wx0 + (size_t)row * 21;
            f16x8 f;
#pragma unroll
            for (int j = 0; j < 8; ++j) {
                int kl = q * 8 + j;
                f[j] = (f16)((kl < 21) ? wx0r[kl] : 0.f);
            }
            B0[16] = f;
        }
        const float* wx1r = Wx1 + (size_t)row * 512;
        const float* wh1r = Wh1 + (size_t)row * 512;
#pragma unroll
        for (int kk = 0; kk < 32; ++kk) {
            int k0 = kk * 32 + q * 8;
            const float* p = (k0 < 512) ? (wx1r + k0) : (wh1r + (k0 - 512));
            B1[kk] = pack8(*(const float4*)p, *(const float4*)(p + 4));
        }
    }
    __syncthreads();

    for (int t = 0; t < T_STEPS; ++t) {
        const int wr = t & 1, rd = wr ^ 1;
        const f16* h0rd = H0g + rd * 4096;
        f16*       h0wr = H0g + wr * 4096;
        const f16* h1rd = H1g + rd * 4096;
        f16*       h1wr = H1g + wr * 4096;

        // ===== phase 1: layer-0 gates (h0(t-1) guaranteed by prev phase 4) ==
        f16x8 xf;
        {
            const float* xp = x + ((size_t)(g * 8 + ln) * 1024 + t) * 21;
#pragma unroll
            for (int j = 0; j < 8; ++j) {
                int kl = q * 8 + j;
                float v = (ln < 8 && kl < 21) ? xp[kl] : 0.f;
                xf[j] = (f16)v;
            }
        }
        f32x4 a0 = {0, 0, 0, 0}, a1 = {0, 0, 0, 0};
#pragma unroll
        for (int kk = 0; kk < 16; kk += 2) {
            f16x8 A0 = load_afrag(h0rd, kk * 32, ln, q);
            f16x8 A1 = load_afrag(h0rd, kk * 32 + 32, ln, q);
            a0 = __builtin_amdgcn_mfma_f32_16x16x32_f16(A0, B0[kk], a0, 0, 0, 0);
            a1 = __builtin_amdgcn_mfma_f32_16x16x32_f16(A1, B0[kk + 1], a1, 0, 0, 0);
        }
        a0 = __builtin_amdgcn_mfma_f32_16x16x32_f16(xf, B0[16], a0, 0, 0, 0);
        f32x4 acc = a0 + a1;
        // D layout: row m=(lane>>4)*4+r (batch), col n=lane&15 (unit)
#pragma unroll
        for (int r = 0; r < 4; ++r) sm.g[w][q * 4 + r][ln] = acc[r];
        __syncthreads();
        if (tid < 128) {
            int b = tid & 7, u = tid >> 3;
            float gi = sm.g[0][b][u] + sm.bias[0][0][u];
            float gf = sm.g[1][b][u] + sm.bias[0][1][u];
            float gg = sm.g[2][b][u] + sm.bias[0][2][u];
            float go = sm.g[3][b][u] + sm.bias[0][3][u];
            float iv = sigm_(gi), fv = sigm_(gf), gv = tanh_(gg), ov = sigm_(go);
            float c = sm.c[0][b][u];
            float cn = fv * c + iv * gv;
            sm.c[0][b][u] = cn;
            h0wr[b * 512 + (cu << 4) + u] = (f16)(ov * tanh_(cn));
        }
        __syncthreads();   // drains vmcnt: stores in L2 before publish
        if (tid == 0)
            __hip_atomic_fetch_add(cntA, 1u, __ATOMIC_RELEASE, __HIP_MEMORY_SCOPE_AGENT);

        // ===== phase 2: wait for h1(t-1) (published end of step t-1) ========
        if (tid == 0) spin_until(cntB, 32u * (unsigned)t);
        __syncthreads();
        __builtin_amdgcn_fence(__ATOMIC_ACQUIRE, "agent");   // one buffer_inv

        // ===== phase 3: out-proj(t-1) on wave 1 + Wh1 @ h1(t-1) =============
        if (t > 0 && tid >= 64 && tid < 128) {
            int wt = tid - 64;            // lane in wave 1
            int pr = wt >> 3, kp = wt & 7;
            int idx = cu * 5 + pr;        // pr<5 valid
            int valid = (pr < 5);
            int b = valid ? idx / 20 : 0, o = valid ? idx % 20 : 0;
            const f16* hp = h1rd + b * 512 + kp * 64;
            const float* wo = Wo + (size_t)o * 512 + kp * 64;
            float a = 0.f;
            if (valid) {
#pragma unroll
                for (int k = 0; k < 64; k += 8) {
                    f16x8 hv = *(const f16x8*)(hp + k);
                    float4 wa = *(const float4*)(wo + k);
                    float4 wb = *(const float4*)(wo + k + 4);
                    a += (float)hv[0] * wa.x + (float)hv[1] * wa.y +
                         (float)hv[2] * wa.z + (float)hv[3] * wa.w +
                         (float)hv[4] * wb.x + (float)hv[5] * wb.y +
                         (float)hv[6] * wb.z + (float)hv[7] * wb.w;
                }
            }
            a += __shfl_down(a, 4, 8);    // all 64 lanes of wave 1 participate
            a += __shfl_down(a, 2, 8);
            a += __shfl_down(a, 1, 8);
            if (valid && kp == 0)
                out[((size_t)(g * 8 + b) * 1024 + (t - 1)) * 20 + o] = sigm_(a + bo[o]);
        }
        f32x4 c0v = {0, 0, 0, 0}, c1v = {0, 0, 0, 0};
#pragma unroll
        for (int kk = 16; kk < 32; kk += 2) {
            f16x8 A0 = load_afrag(h1rd, kk * 32 - 512, ln, q);
            f16x8 A1 = load_afrag(h1rd, kk * 32 - 480, ln, q);
            c0v = __builtin_amdgcn_mfma_f32_16x16x32_f16(A0, B1[kk], c0v, 0, 0, 0);
            c1v = __builtin_amdgcn_mfma_f32_16x16x32_f16(A1, B1[kk + 1], c1v, 0, 0, 0);
        }

        // ===== phase 4: wait for h0(t) (published in phase 1) ===============
        if (tid == 0) spin_until(cntA, 32u * (unsigned)(t + 1));
        __syncthreads();
        __builtin_amdgcn_fence(__ATOMIC_ACQUIRE, "agent");   // one buffer_inv

        // ===== phase 5: Wx1 @ h0(t), activation, publish h1(t) ==============
#pragma unroll
        for (int kk = 0; kk < 16; kk += 2) {
            f16x8 A0 = load_afrag(h0wr, kk * 32, ln, q);
            f16x8 A1 = load_afrag(h0wr, kk * 32 + 32, ln, q);
            c0v = __builtin_amdgcn_mfma_f32_16x16x32_f16(A0, B1[kk], c0v, 0, 0, 0);
            c1v = __builtin_amdgcn_mfma_f32_16x16x32_f16(A1, B1[kk + 1], c1v, 0, 0, 0);
        }
        acc = c0v + c1v;
#pragma unroll
        for (int r = 0; r < 4; ++r) sm.g[w][q * 4 + r][ln] = acc[r];
        __syncthreads();
        if (tid < 128) {
            int b = tid & 7, u = tid >> 3;
            float gi = sm.g[0][b][u] + sm.bias[1][0][u];
            float gf = sm.g[1][b][u] + sm.bias[1][1][u];
            float gg = sm.g[2][b][u] + sm.bias[1][2][u];
            float go = sm.g[3][b][u] + sm.bias[1][3][u];
            float iv = sigm_(gi), fv = sigm_(gf), gv = tanh_(gg), ov = sigm_(go);
            float c = sm.c[1][b][u];
            float cn = fv * c + iv * gv;
            sm.c[1][b][u] = cn;
            h1wr[b * 512 + (cu << 4) + u] = (f16)(ov * tanh_(cn));
        }
        __syncthreads();
        if (tid == 0)
            __hip_atomic_fetch_add(cntB, 1u, __ATOMIC_RELEASE, __HIP_MEMORY_SCOPE_AGENT);
    }

    // ===== epilogue: out-projection for t = T-1 =============================
    if (tid == 0) spin_until(cntB, 32u * (unsigned)T_STEPS);
    __syncthreads();
    __builtin_amdgcn_fence(__ATOMIC_ACQUIRE, "agent");
    {
        const f16* h1p = H1g + ((T_STEPS - 1) & 1) * 4096;
        if (tid >= 64 && tid < 128) {
            int wt = tid - 64;
            int pr = wt >> 3, kp = wt & 7;
            int idx = cu * 5 + pr;
            int valid = (pr < 5);
            int b = valid ? idx / 20 : 0, o = valid ? idx % 20 : 0;
            const f16* hp = h1p + b * 512 + kp * 64;
            const float* wo = Wo + (size_t)o * 512 + kp * 64;
            float a = 0.f;
            if (valid) {
#pragma unroll
                for (int k = 0; k < 64; k += 8) {
                    f16x8 hv = *(const f16x8*)(hp + k);
                    float4 wa = *(const float4*)(wo + k);
                    float4 wb = *(const float4*)(wo + k + 4);
                    a += (float)hv[0] * wa.x + (float)hv[1] * wa.y +
                         (float)hv[2] * wa.z + (float)hv[3] * wa.w +
                         (float)hv[4] * wb.x + (float)hv[5] * wb.y +
                         (float)hv[6] * wb.z + (float)hv[7] * wb.w;
                }
            }
            a += __shfl_down(a, 4, 8);
            a += __shfl_down(a, 2, 8);
            a += __shfl_down(a, 1, 8);
            if (valid && kp == 0)
                out[((size_t)(g * 8 + b) * 1024 + (T_STEPS - 1)) * 20 + o] =
                    sigm_(a + bo[o]);
        }
    }
}

extern "C" void kernel_launch(void* const* d_in, const int* in_sizes, int n_in,
                              void* d_out, int out_size, void* d_ws, size_t ws_size,
                              hipStream_t stream) {
    const float* x   = (const float*)d_in[0];
    const float* Wx0 = (const float*)d_in[1];
    const float* bx0 = (const float*)d_in[2];
    const float* Wh0 = (const float*)d_in[3];
    const float* Wx1 = (const float*)d_in[4];
    const float* bx1 = (const float*)d_in[5];
    const float* Wh1 = (const float*)d_in[6];
    const float* Wo  = (const float*)d_in[7];
    const float* bo  = (const float*)d_in[8];
    float* out = (float*)d_out;
    char*  ws  = (char*)d_ws;

    if (ws_size < (size_t)WS_NEED) return;   // fail visibly (out stays poisoned)

    zero_ws_kernel<<<64, 256, 0, stream>>>((unsigned*)ws, WS_NEED / 4);
    lstm_persist<<<256, 256, 0, stream>>>(x, Wx0, bx0, Wh0, Wx1, bx1, Wh1,
                                          Wo, bo, out, ws);
}

// Round 3
// 6153.221 us; speedup vs baseline: 5.0335x; 4.3868x over previous
//
#include <hip/hip_runtime.h>

// ---------------------------------------------------------------------------
// Persistent 2-layer LSTM, MI355X. Round 3.
// 8 groups (blockIdx%8), 32 WGs/group, 8 batches/group. Weights in VGPRs.
// Coherence protocol: ALL h-plane traffic uses sc0|sc1 bypass ops (relaxed
// SYSTEM-scope atomics) -> coherent at LLC by construction. ZERO fences,
// ZERO buffer_inv / buffer_wbl2 in the steady state (round-2's 13 us/crossing
// was 32x wbl2 + 128x inv per XCD per crossing). x/Wo stay warm in L2.
// h planes are staged into LDS once per GEMM phase; MFMA A-frags from LDS.
// ---------------------------------------------------------------------------

#define T_STEPS 1024
#define WS_BAR_OFF 0                      // 8 groups * 2 counters * 128 B
#define WS_H0_OFF  2048                   // [8 g][2 parity][8 batch][512] f16
#define WS_H1_OFF  (2048 + 8*2*8*512*2)
#define WS_NEED    (WS_H1_OFF + 8*2*8*512*2)   // 264192 bytes

typedef _Float16 f16;
typedef _Float16 f16x8 __attribute__((ext_vector_type(8)));
typedef float    f32x4 __attribute__((ext_vector_type(4)));
typedef unsigned long long u64;

#define HP_STRIDE 520   // padded LDS plane row stride (f16): breaks bank conflicts

__device__ __forceinline__ float sigm_(float x) {
    x = fminf(fmaxf(x, -30.f), 30.f);
    return 1.f / (1.f + __expf(-x));
}
__device__ __forceinline__ float tanh_(float x) {
    x = fminf(fmaxf(x, -15.f), 15.f);
    float e = __expf(-2.f * x);
    return (1.f - e) / (1.f + e);
}

// A-fragment for 16x16x32 f16 MFMA from the padded LDS plane.
// A[m=lane&15][k=(lane>>4)*8+j]; m = batch (0..7 valid, 8..15 -> zeros).
__device__ __forceinline__ f16x8 afrag_lds(const f16* __restrict__ hp, int kbase,
                                           int b, int q) {
    if (b < 8) {
        return *(const f16x8*)(hp + b * HP_STRIDE + kbase + q * 8);
    }
    f16x8 z = {(_Float16)0, (_Float16)0, (_Float16)0, (_Float16)0,
               (_Float16)0, (_Float16)0, (_Float16)0, (_Float16)0};
    return z;
}

__device__ __forceinline__ f16x8 pack8(float4 a, float4 b) {
    f16x8 f;
    f[0] = (f16)a.x; f[1] = (f16)a.y; f[2] = (f16)a.z; f[3] = (f16)a.w;
    f[4] = (f16)b.x; f[5] = (f16)b.y; f[6] = (f16)b.z; f[7] = (f16)b.w;
    return f;
}

// Stage one 8 KB h-plane (8 batches x 512 f16, contiguous in global) into the
// padded LDS plane. Bypass (sc0|sc1) loads -> always read the LLC, never a
// stale L2 line; no fence needed. 4 x 8B per thread, issued back-to-back.
__device__ __forceinline__ void stage_plane(const f16* __restrict__ gp,
                                            f16* __restrict__ dst, int tid) {
    const u64* g8 = (const u64*)gp;
    u64 v[4];
#pragma unroll
    for (int j = 0; j < 4; ++j)
        v[j] = __hip_atomic_load(g8 + tid * 4 + j, __ATOMIC_RELAXED,
                                 __HIP_MEMORY_SCOPE_SYSTEM);
#pragma unroll
    for (int j = 0; j < 4; ++j) {
        int idx = (tid * 4 + j) * 4;              // f16 index in plane
        int b = idx >> 9, u = idx & 511;
        *(u64*)(dst + b * HP_STRIDE + u) = v[j];
    }
}

// RELAXED poll — no cache maintenance per iteration.
__device__ __forceinline__ void spin_until(unsigned* cnt, unsigned target) {
    int spins = 0;
    while (__hip_atomic_load(cnt, __ATOMIC_RELAXED, __HIP_MEMORY_SCOPE_AGENT) < target) {
        __builtin_amdgcn_s_sleep(1);
        if (++spins > (1 << 22)) break;   // anti-hang safety valve
    }
}

__global__ void zero_ws_kernel(unsigned* __restrict__ p, int ndw) {
    int i = blockIdx.x * blockDim.x + threadIdx.x;
    int stride = gridDim.x * blockDim.x;
    for (; i < ndw; i += stride) p[i] = 0u;
}

__global__ __launch_bounds__(256, 1)
void lstm_persist(const float* __restrict__ x,
                  const float* __restrict__ Wx0, const float* __restrict__ bx0,
                  const float* __restrict__ Wh0,
                  const float* __restrict__ Wx1, const float* __restrict__ bx1,
                  const float* __restrict__ Wh1,
                  const float* __restrict__ Wo,  const float* __restrict__ bo,
                  float* __restrict__ out, char* __restrict__ ws) {
    struct SM {
        float g[4][16][16];                    // per-wave gate tiles
        float c[2][8][16];                     // cell state [layer][b][u]
        float bias[2][4][16];                  // bx slices
        __align__(8)  f16 hout[8][16];         // activation -> packed store
        __align__(16) f16 hplane[8 * HP_STRIDE]; // staged h plane (padded)
        char  pad[70 * 1024];                  // force <=1 WG/CU
    };
    __shared__ SM sm;
    const int tid = threadIdx.x;
    if (tid == 0x00FFFFFFu) sm.pad[0] = 1;     // keep pad alive

    const int bid  = blockIdx.x;
    const int g    = bid & 7;     // group
    const int cu   = bid >> 3;    // 0..31 within group
    const int w    = tid >> 6;    // wave id = gate type (i,f,g,o)
    const int lane = tid & 63;
    const int ln   = lane & 15;
    const int q    = lane >> 4;

    unsigned* cntA = (unsigned*)(ws + WS_BAR_OFF) + g * 64;        // h0 barrier
    unsigned* cntB = (unsigned*)(ws + WS_BAR_OFF) + g * 64 + 32;   // h1 barrier
    f16* H0g = (f16*)(ws + WS_H0_OFF) + g * 8192;   // 2 planes x (8*512)
    f16* H1g = (f16*)(ws + WS_H1_OFF) + g * 8192;

    // ---- LDS init -------------------------------------------------------
    ((float*)sm.c)[tid & 255] = 0.f;               // 2*8*16 = 256 floats
    if (tid < 128) {
        int u = tid & 15, w2 = (tid >> 4) & 3, L = tid >> 6;
        const float* bx = L ? bx1 : bx0;
        sm.bias[L][w2][u] = bx[(w2 << 9) + (cu << 4) + u];
    }

    // ---- persistent weight fragments in registers -----------------------
    const int row = (w << 9) + (cu << 4) + ln;      // gate row in [0,2048)
    f16x8 B0[17];   // layer0: k = [Wh0(512) ; Wx0(21 pad 32)]
    f16x8 B1[32];   // layer1: k = [Wx1(512) ; Wh1(512)]
    {
        const float* wh0r = Wh0 + (size_t)row * 512;
#pragma unroll
        for (int kk = 0; kk < 16; ++kk) {
            const float* p = wh0r + kk * 32 + q * 8;
            B0[kk] = pack8(*(const float4*)p, *(const float4*)(p + 4));
        }
        {
            const float* wx0r = Wx0 + (size_t)row * 21;
            f16x8 f;
#pragma unroll
            for (int j = 0; j < 8; ++j) {
                int kl = q * 8 + j;
                f[j] = (f16)((kl < 21) ? wx0r[kl] : 0.f);
            }
            B0[16] = f;
        }
        const float* wx1r = Wx1 + (size_t)row * 512;
        const float* wh1r = Wh1 + (size_t)row * 512;
#pragma unroll
        for (int kk = 0; kk < 32; ++kk) {
            int k0 = kk * 32 + q * 8;
            const float* p = (k0 < 512) ? (wx1r + k0) : (wh1r + (k0 - 512));
            B1[kk] = pack8(*(const float4*)p, *(const float4*)(p + 4));
        }
    }
    __syncthreads();

    for (int t = 0; t < T_STEPS; ++t) {
        const int wr = t & 1, rd = wr ^ 1;
        const f16* h0rd = H0g + rd * 4096;
        f16*       h0wr = H0g + wr * 4096;
        const f16* h1rd = H1g + rd * 4096;
        f16*       h1wr = H1g + wr * 4096;

        // ===== phase 1: layer-0 gates (h0(t-1) ready per prior phase-4) ====
        f16x8 xf;
        {
            const float* xp = x + ((size_t)(g * 8 + ln) * 1024 + t) * 21;
#pragma unroll
            for (int j = 0; j < 8; ++j) {
                int kl = q * 8 + j;
                float v = (ln < 8 && kl < 21) ? xp[kl] : 0.f;
                xf[j] = (f16)v;
            }
        }
        stage_plane(h0rd, sm.hplane, tid);
        __syncthreads();
        f32x4 a0 = {0, 0, 0, 0}, a1 = {0, 0, 0, 0};
#pragma unroll
        for (int kk = 0; kk < 16; kk += 2) {
            f16x8 A0 = afrag_lds(sm.hplane, kk * 32, ln, q);
            f16x8 A1 = afrag_lds(sm.hplane, kk * 32 + 32, ln, q);
            a0 = __builtin_amdgcn_mfma_f32_16x16x32_f16(A0, B0[kk], a0, 0, 0, 0);
            a1 = __builtin_amdgcn_mfma_f32_16x16x32_f16(A1, B0[kk + 1], a1, 0, 0, 0);
        }
        a0 = __builtin_amdgcn_mfma_f32_16x16x32_f16(xf, B0[16], a0, 0, 0, 0);
        f32x4 acc = a0 + a1;
#pragma unroll
        for (int r = 0; r < 4; ++r) sm.g[w][q * 4 + r][ln] = acc[r];
        __syncthreads();
        if (tid < 128) {
            int b = tid & 7, u = tid >> 3;
            float gi = sm.g[0][b][u] + sm.bias[0][0][u];
            float gf = sm.g[1][b][u] + sm.bias[0][1][u];
            float gg = sm.g[2][b][u] + sm.bias[0][2][u];
            float go = sm.g[3][b][u] + sm.bias[0][3][u];
            float iv = sigm_(gi), fv = sigm_(gf), gv = tanh_(gg), ov = sigm_(go);
            float c = sm.c[0][b][u];
            float cn = fv * c + iv * gv;
            sm.c[0][b][u] = cn;
            sm.hout[b][u] = (f16)(ov * tanh_(cn));
        }
        __syncthreads();
        if (tid < 32) {        // packed bypass stores -> LLC, no L2 dirty lines
            int b = tid >> 2, j = tid & 3;
            u64 v = *(const u64*)&sm.hout[b][j * 4];
            __hip_atomic_store((u64*)(h0wr + b * 512 + (cu << 4) + j * 4), v,
                               __ATOMIC_RELAXED, __HIP_MEMORY_SCOPE_SYSTEM);
        }
        __syncthreads();       // drains vmcnt: stores complete at LLC
        if (tid == 0)
            __hip_atomic_fetch_add(cntA, 1u, __ATOMIC_RELAXED, __HIP_MEMORY_SCOPE_AGENT);

        // ===== phase 2: wait h1(t-1), stage it =============================
        if (tid == 0) spin_until(cntB, 32u * (unsigned)t);
        __syncthreads();
        stage_plane(h1rd, sm.hplane, tid);
        __syncthreads();

        // ===== phase 3: out-proj(t-1) on wave 1 + Wh1 @ h1(t-1) ============
        if (t > 0 && tid >= 64 && tid < 128) {
            int wt = tid - 64;            // lane in wave 1
            int pr = wt >> 3, kp = wt & 7;
            int idx = cu * 5 + pr;        // pr<5 valid
            int valid = (pr < 5);
            int b = valid ? idx / 20 : 0, o = valid ? idx % 20 : 0;
            const f16* hp = sm.hplane + b * HP_STRIDE + kp * 64;
            const float* wo = Wo + (size_t)o * 512 + kp * 64;
            float a = 0.f;
            if (valid) {
#pragma unroll
                for (int k = 0; k < 64; k += 8) {
                    f16x8 hv = *(const f16x8*)(hp + k);
                    float4 wa = *(const float4*)(wo + k);
                    float4 wb = *(const float4*)(wo + k + 4);
                    a += (float)hv[0] * wa.x + (float)hv[1] * wa.y +
                         (float)hv[2] * wa.z + (float)hv[3] * wa.w +
                         (float)hv[4] * wb.x + (float)hv[5] * wb.y +
                         (float)hv[6] * wb.z + (float)hv[7] * wb.w;
                }
            }
            a += __shfl_down(a, 4, 8);
            a += __shfl_down(a, 2, 8);
            a += __shfl_down(a, 1, 8);
            if (valid && kp == 0)
                out[((size_t)(g * 8 + b) * 1024 + (t - 1)) * 20 + o] = sigm_(a + bo[o]);
        }
        f32x4 c0v = {0, 0, 0, 0}, c1v = {0, 0, 0, 0};
#pragma unroll
        for (int kk = 16; kk < 32; kk += 2) {
            f16x8 A0 = afrag_lds(sm.hplane, kk * 32 - 512, ln, q);
            f16x8 A1 = afrag_lds(sm.hplane, kk * 32 - 480, ln, q);
            c0v = __builtin_amdgcn_mfma_f32_16x16x32_f16(A0, B1[kk], c0v, 0, 0, 0);
            c1v = __builtin_amdgcn_mfma_f32_16x16x32_f16(A1, B1[kk + 1], c1v, 0, 0, 0);
        }

        // ===== phase 4: wait h0(t), stage it ===============================
        if (tid == 0) spin_until(cntA, 32u * (unsigned)(t + 1));
        __syncthreads();
        stage_plane(h0wr, sm.hplane, tid);
        __syncthreads();

        // ===== phase 5: Wx1 @ h0(t), activation, publish h1(t) =============
#pragma unroll
        for (int kk = 0; kk < 16; kk += 2) {
            f16x8 A0 = afrag_lds(sm.hplane, kk * 32, ln, q);
            f16x8 A1 = afrag_lds(sm.hplane, kk * 32 + 32, ln, q);
            c0v = __builtin_amdgcn_mfma_f32_16x16x32_f16(A0, B1[kk], c0v, 0, 0, 0);
            c1v = __builtin_amdgcn_mfma_f32_16x16x32_f16(A1, B1[kk + 1], c1v, 0, 0, 0);
        }
        acc = c0v + c1v;
#pragma unroll
        for (int r = 0; r < 4; ++r) sm.g[w][q * 4 + r][ln] = acc[r];
        __syncthreads();
        if (tid < 128) {
            int b = tid & 7, u = tid >> 3;
            float gi = sm.g[0][b][u] + sm.bias[1][0][u];
            float gf = sm.g[1][b][u] + sm.bias[1][1][u];
            float gg = sm.g[2][b][u] + sm.bias[1][2][u];
            float go = sm.g[3][b][u] + sm.bias[1][3][u];
            float iv = sigm_(gi), fv = sigm_(gf), gv = tanh_(gg), ov = sigm_(go);
            float c = sm.c[1][b][u];
            float cn = fv * c + iv * gv;
            sm.c[1][b][u] = cn;
            sm.hout[b][u] = (f16)(ov * tanh_(cn));
        }
        __syncthreads();
        if (tid < 32) {
            int b = tid >> 2, j = tid & 3;
            u64 v = *(const u64*)&sm.hout[b][j * 4];
            __hip_atomic_store((u64*)(h1wr + b * 512 + (cu << 4) + j * 4), v,
                               __ATOMIC_RELAXED, __HIP_MEMORY_SCOPE_SYSTEM);
        }
        __syncthreads();
        if (tid == 0)
            __hip_atomic_fetch_add(cntB, 1u, __ATOMIC_RELAXED, __HIP_MEMORY_SCOPE_AGENT);
    }

    // ===== epilogue: out-projection for t = T-1 =============================
    if (tid == 0) spin_until(cntB, 32u * (unsigned)T_STEPS);
    __syncthreads();
    stage_plane(H1g + ((T_STEPS - 1) & 1) * 4096, sm.hplane, tid);
    __syncthreads();
    if (tid >= 64 && tid < 128) {
        int wt = tid - 64;
        int pr = wt >> 3, kp = wt & 7;
        int idx = cu * 5 + pr;
        int valid = (pr < 5);
        int b = valid ? idx / 20 : 0, o = valid ? idx % 20 : 0;
        const f16* hp = sm.hplane + b * HP_STRIDE + kp * 64;
        const float* wo = Wo + (size_t)o * 512 + kp * 64;
        float a = 0.f;
        if (valid) {
#pragma unroll
            for (int k = 0; k < 64; k += 8) {
                f16x8 hv = *(const f16x8*)(hp + k);
                float4 wa = *(const float4*)(wo + k);
                float4 wb = *(const float4*)(wo + k + 4);
                a += (float)hv[0] * wa.x + (float)hv[1] * wa.y +
                     (float)hv[2] * wa.z + (float)hv[3] * wa.w +
                     (float)hv[4] * wb.x + (float)hv[5] * wb.y +
                     (float)hv[6] * wb.z + (float)hv[7] * wb.w;
            }
        }
        a += __shfl_down(a, 4, 8);
        a += __shfl_down(a, 2, 8);
        a += __shfl_down(a, 1, 8);
        if (valid && kp == 0)
            out[((size_t)(g * 8 + b) * 1024 + (T_STEPS - 1)) * 20 + o] =
                sigm_(a + bo[o]);
    }
}

extern "C" void kernel_launch(void* const* d_in, const int* in_sizes, int n_in,
                              void* d_out, int out_size, void* d_ws, size_t ws_size,
                              hipStream_t stream) {
    const float* x   = (const float*)d_in[0];
    const float* Wx0 = (const float*)d_in[1];
    const float* bx0 = (const float*)d_in[2];
    const float* Wh0 = (const float*)d_in[3];
    const float* Wx1 = (const float*)d_in[4];
    const float* bx1 = (const float*)d_in[5];
    const float* Wh1 = (const float*)d_in[6];
    const float* Wo  = (const float*)d_in[7];
    const float* bo  = (const float*)d_in[8];
    float* out = (float*)d_out;
    char*  ws  = (char*)d_ws;

    if (ws_size < (size_t)WS_NEED) return;   // fail visibly (out stays poisoned)

    zero_ws_kernel<<<64, 256, 0, stream>>>((unsigned*)ws, WS_NEED / 4);
    lstm_persist<<<256, 256, 0, stream>>>(x, Wx0, bx0, Wh0, Wx1, bx1, Wh1,
                                          Wo, bo, out, ws);
}